// Round 1
// baseline (240.158 us; speedup 1.0000x reference)
//
#include <hip/hip_runtime.h>
#include <hip/hip_bf16.h>

#define NN 50000
#define EE 800000
#define DD 128
#define CB 196      // coarse buckets of 256 nodes (196*256 = 50176)
#define NFB 1563    // fine buckets of 32 nodes (mega grid)
#define EBLK 4096
#define NEB 196     // ceil(EE/EBLK)
#define XSB 3125    // xs-scale blocks: 3125*256 = 800000 = NN*16 bf16x8 items
#define SCB 391     // scatter blocks: 391*2048 = 800768 >= EE

typedef __attribute__((ext_vector_type(8))) short bf16x8;
typedef __attribute__((ext_vector_type(4))) float f32x4;

static __device__ __forceinline__ unsigned short f2bf(float f) {
  union { float f; unsigned u; } v; v.f = f;
  unsigned r = v.u + 0x7FFFu + ((v.u >> 16) & 1u);
  return (unsigned short)(r >> 16);
}
static __device__ __forceinline__ float bf2f(unsigned short h) {
  union { unsigned u; float f; } v; v.u = ((unsigned)h) << 16;
  return v.f;
}

// blocks [0,196): coarse LDS histogram of dst>>8 AND direct global deg histogram.
// blocks [196,228): Wt[n][k] bf16 combined (k<128: W_gcn, k>=128: W_lin).
// blocks [228,1791): x -> bf16 xb (unscaled).
__global__ __launch_bounds__(256) void k_p0(
    const int* __restrict__ dst, int* __restrict__ coarseCnt,
    int* __restrict__ deg,
    const float* __restrict__ Wg, const float* __restrict__ Wl,
    unsigned short* __restrict__ Wt, const float4* __restrict__ x4,
    ushort4* __restrict__ xb4) {
  int b = blockIdx.x, t = threadIdx.x;
  if (b < NEB) {
    __shared__ int cnt[CB];
    for (int i = t; i < CB; i += 256) cnt[i] = 0;
    __syncthreads();
    int e0 = b * EBLK;
    for (int i = t; i < EBLK; i += 256) {
      int e = e0 + i;
      if (e < EE) {
        int d = dst[e];
        atomicAdd(&cnt[d >> 8], 1);   // coarse (LDS, for cross-chunk prefix)
        atomicAdd(&deg[d], 1);        // fine (global, L2-resident 200 KB)
      }
    }
    __syncthreads();
    for (int i = t; i < CB; i += 256)
      if (cnt[i]) atomicAdd(&coarseCnt[i], cnt[i]);
  } else if (b < NEB + 32) {
    for (int i = (b - NEB) * 256 + t; i < DD * 256; i += 32 * 256) {
      int n = i >> 8, k = i & 255;
      float v = (k < 128) ? Wg[k * DD + n] : Wl[(k - 128) * DD + n];
      Wt[i] = f2bf(v);
    }
  } else {
    int base = (b - NEB - 32) * 1024 + t;
#pragma unroll
    for (int k = 0; k < 4; k++) {
      int i = base + k * 256;
      if (i < NN * 32) {
        float4 v = x4[i];
        ushort4 o;
        o.x = f2bf(v.x); o.y = f2bf(v.y); o.z = f2bf(v.z); o.w = f2bf(v.w);
        xb4[i] = o;
      }
    }
  }
}

// One block per 256-node chunk: prefix over coarseCnt + LDS scan of deg chunk
// -> rowStart, cursor (scatter base), dinv. Tiny.
__global__ __launch_bounds__(256) void k_scan(
    const int* __restrict__ coarseCnt, const int* __restrict__ deg,
    int* __restrict__ rowStart, int* __restrict__ cursor,
    float* __restrict__ dinv) {
  __shared__ int lscan[256];
  __shared__ int wsum[4];
  int b = blockIdx.x, t = threadIdx.x;
  int n0 = b << 8;
  int partial = 0;
  for (int i = t; i < b; i += 256) partial += coarseCnt[i];
#pragma unroll
  for (int off = 32; off > 0; off >>= 1) partial += __shfl_xor(partial, off);
  if ((t & 63) == 0) wsum[t >> 6] = partial;
  int n = n0 + t;
  int dg = (n < NN) ? deg[n] : 0;
  lscan[t] = dg;
  for (int off = 1; off < 256; off <<= 1) {
    __syncthreads();
    int tmp = (t >= off) ? lscan[t - off] : 0;
    __syncthreads();
    if (t >= off) lscan[t] += tmp;
  }
  __syncthreads();
  int start = wsum[0] + wsum[1] + wsum[2] + wsum[3];
  if (n < NN) {
    int rs = start + lscan[t] - dg;
    rowStart[n] = rs;
    cursor[n] = rs;
    dinv[n] = rsqrtf((float)(dg + 1));
  }
}

// blocks [0,XSB): xs = dinv * xb (streaming, coalesced).
// blocks [XSB,XSB+SCB): edge scatter via global atomic cursor (L2-resident).
__global__ __launch_bounds__(256) void k_fill(
    const int* __restrict__ src, const int* __restrict__ dst,
    int* __restrict__ cursor, const unsigned short* __restrict__ xb,
    const float* __restrict__ dinv, unsigned short* __restrict__ xs,
    unsigned short* __restrict__ srcU16) {
  int b = blockIdx.x, t = threadIdx.x;
  if (b < XSB) {
    int i = b * 256 + t;            // one bf16x8 per thread; 3125*256 == NN*16
    int row = i >> 4;
    float di = dinv[row];
    bf16x8 v = *(const bf16x8*)(xb + (size_t)i * 8);
    bf16x8 o;
#pragma unroll
    for (int k = 0; k < 8; k++) o[k] = (short)f2bf(bf2f((unsigned short)v[k]) * di);
    *(bf16x8*)(xs + (size_t)i * 8) = o;
  } else {
    int e0 = (b - XSB) * 2048 + t;
#pragma unroll
    for (int k = 0; k < 8; k++) {
      int e = e0 + k * 256;
      if (e < EE) {
        int d = dst[e];
        int pos = atomicAdd(&cursor[d], 1);
        srcU16[pos] = (unsigned short)src[e];
      }
    }
  }
}

// Gather a node's CSR range into acc[8] (lane slice r*8), 8 rows in flight.
static __device__ __forceinline__ void gather16(
    const unsigned short* __restrict__ xs, const unsigned short* __restrict__ srcU16,
    int js, int cnt, int r, int srcLaneBase, float* acc) {
  for (int base = 0; base < cnt; base += 16) {
    int idx = (base + r < cnt) ? (int)srcU16[js + base + r] : 0;
    int m = cnt - base; if (m > 16) m = 16;
    int j = 0;
    for (; j + 8 <= m; j += 8) {
      int s0 = __shfl(idx, srcLaneBase + j);
      int s1 = __shfl(idx, srcLaneBase + j + 1);
      int s2 = __shfl(idx, srcLaneBase + j + 2);
      int s3 = __shfl(idx, srcLaneBase + j + 3);
      int s4 = __shfl(idx, srcLaneBase + j + 4);
      int s5 = __shfl(idx, srcLaneBase + j + 5);
      int s6 = __shfl(idx, srcLaneBase + j + 6);
      int s7 = __shfl(idx, srcLaneBase + j + 7);
      bf16x8 v0 = *(const bf16x8*)(xs + (size_t)s0 * DD + r * 8);
      bf16x8 v1 = *(const bf16x8*)(xs + (size_t)s1 * DD + r * 8);
      bf16x8 v2 = *(const bf16x8*)(xs + (size_t)s2 * DD + r * 8);
      bf16x8 v3 = *(const bf16x8*)(xs + (size_t)s3 * DD + r * 8);
      bf16x8 v4 = *(const bf16x8*)(xs + (size_t)s4 * DD + r * 8);
      bf16x8 v5 = *(const bf16x8*)(xs + (size_t)s5 * DD + r * 8);
      bf16x8 v6 = *(const bf16x8*)(xs + (size_t)s6 * DD + r * 8);
      bf16x8 v7 = *(const bf16x8*)(xs + (size_t)s7 * DD + r * 8);
#pragma unroll
      for (int k = 0; k < 8; k++) acc[k] += bf2f((unsigned short)v0[k]);
#pragma unroll
      for (int k = 0; k < 8; k++) acc[k] += bf2f((unsigned short)v1[k]);
#pragma unroll
      for (int k = 0; k < 8; k++) acc[k] += bf2f((unsigned short)v2[k]);
#pragma unroll
      for (int k = 0; k < 8; k++) acc[k] += bf2f((unsigned short)v3[k]);
#pragma unroll
      for (int k = 0; k < 8; k++) acc[k] += bf2f((unsigned short)v4[k]);
#pragma unroll
      for (int k = 0; k < 8; k++) acc[k] += bf2f((unsigned short)v5[k]);
#pragma unroll
      for (int k = 0; k < 8; k++) acc[k] += bf2f((unsigned short)v6[k]);
#pragma unroll
      for (int k = 0; k < 8; k++) acc[k] += bf2f((unsigned short)v7[k]);
    }
    for (; j < m; j++) {
      int s = __shfl(idx, srcLaneBase + j);
      bf16x8 v = *(const bf16x8*)(xs + (size_t)s * DD + r * 8);
#pragma unroll
      for (int k = 0; k < 8; k++) acc[k] += bf2f((unsigned short)v[k]);
    }
  }
}

// One block per 32-node bucket, 512 threads: 32 groups x 1 node gather
// (12500 waves offered -> agg2-level occupancy), then waves 0-1 run the
// MFMA [agg|x]@[Wg;Wl] + bias + LayerNorm epilogue; waves 2-7 exit.
__global__ __launch_bounds__(512) void k_mega4(
    const unsigned short* __restrict__ xs, const unsigned short* __restrict__ xb,
    const int* __restrict__ rowStart, const int* __restrict__ deg,
    const unsigned short* __restrict__ srcU16, const float* __restrict__ dinv,
    const unsigned short* __restrict__ Wt, const float* __restrict__ bgcn,
    const float* __restrict__ lnw, const float* __restrict__ lnb,
    float* __restrict__ out) {
  __shared__ unsigned short abuf[32 * 136];  // 8.7 KB
  int b = blockIdx.x, t = threadIdx.x;
  int n0 = b * 32;
  int g = t >> 4, r = t & 15;
  int lane = t & 63;
  int srcLaneBase = lane & 48;
  int node = n0 + g;
  bool valid = (node < NN);
  int nc = valid ? node : (NN - 1);
  float acc[8];
  {  // self-loop init from pre-scaled xs
    bf16x8 va = *(const bf16x8*)(xs + (size_t)nc * DD + r * 8);
#pragma unroll
    for (int k = 0; k < 8; k++) acc[k] = bf2f((unsigned short)va[k]);
  }
  int js = valid ? rowStart[nc] : 0;
  int cnt = valid ? deg[nc] : 0;
  gather16(xs, srcU16, js, cnt, r, srcLaneBase, acc);
  {
    float d = dinv[nc];
    bf16x8 o;
#pragma unroll
    for (int k = 0; k < 8; k++) o[k] = valid ? (short)f2bf(acc[k] * d) : (short)0;
    *(bf16x8*)&abuf[g * 136 + r * 8] = o;
  }
  __syncthreads();
  if (t < 128) {  // waves 0,1: two 16-row MFMA tiles + fused LayerNorm
    int w = t >> 6, lane2 = t & 63;
    int quad = lane2 >> 4, rr = lane2 & 15;
    int mloc = w * 16 + rr;
    int rowA = n0 + mloc; int rc = (rowA < NN) ? rowA : (NN - 1);
    f32x4 zero = {0.f, 0.f, 0.f, 0.f};
    f32x4 macc[8];
#pragma unroll
    for (int i = 0; i < 8; i++) macc[i] = zero;
#pragma unroll
    for (int ks = 0; ks < 8; ks++) {
      bf16x8 a;
      if (ks < 4) a = *(const bf16x8*)&abuf[mloc * 136 + ks * 32 + quad * 8];
      else        a = *(const bf16x8*)(xb + (size_t)rc * DD + (ks - 4) * 32 + quad * 8);
#pragma unroll
      for (int nt = 0; nt < 8; nt++) {
        bf16x8 bb = *(const bf16x8*)(Wt + (size_t)(nt * 16 + rr) * 256 + ks * 32 + quad * 8);
        macc[nt] = __builtin_amdgcn_mfma_f32_16x16x32_bf16(a, bb, macc[nt], 0, 0, 0);
      }
    }
    float bg[8], lw[8], lb[8];
#pragma unroll
    for (int nt = 0; nt < 8; nt++) {
      int col = nt * 16 + rr;
      bg[nt] = bgcn[col] + 1e-6f;
      lw[nt] = lnw[col];
      lb[nt] = lnb[col];
    }
#pragma unroll
    for (int reg = 0; reg < 4; reg++) {
      float y[8];
      float s1 = 0.f, s2 = 0.f;
#pragma unroll
      for (int nt = 0; nt < 8; nt++) {
        y[nt] = macc[nt][reg] + bg[nt];
        s1 += y[nt];
        s2 += y[nt] * y[nt];
      }
#pragma unroll
      for (int off = 1; off < 16; off <<= 1) {
        s1 += __shfl_xor(s1, off);
        s2 += __shfl_xor(s2, off);
      }
      float mu = s1 * (1.0f / 128.0f);
      float var = s2 * (1.0f / 128.0f) - mu * mu;
      float inv = rsqrtf(var + 1e-5f);
      int row = n0 + w * 16 + quad * 4 + reg;
      if (row < NN) {
#pragma unroll
        for (int nt = 0; nt < 8; nt++) {
          out[(size_t)row * DD + nt * 16 + rr] = (y[nt] - mu) * inv * lw[nt] + lb[nt];
        }
      }
    }
  }
}

extern "C" void kernel_launch(void* const* d_in, const int* in_sizes, int n_in,
                              void* d_out, int out_size, void* d_ws, size_t ws_size,
                              hipStream_t stream) {
  const int* adj = (const int*)d_in[0];
  const float* x = (const float*)d_in[1];
  const float* Wg = (const float*)d_in[2];
  const float* bg = (const float*)d_in[3];
  const float* Wl = (const float*)d_in[4];
  const float* lw = (const float*)d_in[5];
  const float* lb = (const float*)d_in[6];
  const int* srcp = adj;
  const int* dstp = adj + EE;
  float* out = (float*)d_out;

  char* ws = (char*)d_ws;
  size_t off = 0;
  auto alloc = [&](size_t bytes) -> void* {
    void* p = ws + off;
    off += (bytes + 255) & ~(size_t)255;
    return p;
  };
  int* zb = (int*)alloc((size_t)512 * 4);   // coarseCnt (196 used)
  int* coarseCnt = zb;
  int* deg = (int*)alloc((size_t)NN * 4);   // contiguous after zb -> one memset
  float* dinv = (float*)alloc((size_t)NN * 4);
  int* rowStart = (int*)alloc((size_t)NN * 4);
  int* cursor = (int*)alloc((size_t)NN * 4);
  unsigned short* srcU16 = (unsigned short*)alloc((size_t)EE * 2);
  unsigned short* xb = (unsigned short*)alloc((size_t)NN * DD * 2);
  unsigned short* xs = (unsigned short*)alloc((size_t)NN * DD * 2);
  unsigned short* Wt = (unsigned short*)alloc((size_t)DD * 256 * 2);
  (void)ws_size; (void)in_sizes; (void)n_in; (void)out_size;

  // zero coarseCnt + deg in one shot (they are adjacent in the workspace)
  hipMemsetAsync(zb, 0, (size_t)512 * 4 + (size_t)NN * 4, stream);
  k_p0<<<NEB + 32 + 1563, 256, 0, stream>>>(dstp, coarseCnt, deg, Wg, Wl, Wt,
                                            (const float4*)x, (ushort4*)xb);
  k_scan<<<CB, 256, 0, stream>>>(coarseCnt, deg, rowStart, cursor, dinv);
  k_fill<<<XSB + SCB, 256, 0, stream>>>(srcp, dstp, cursor, xb, dinv, xs, srcU16);
  k_mega4<<<NFB, 512, 0, stream>>>(xs, xb, rowStart, deg, srcU16, dinv, Wt,
                                   bg, lw, lb, out);
}

// Round 2
// 200.142 us; speedup vs baseline: 1.1999x; 1.1999x over previous
//
#include <hip/hip_runtime.h>
#include <hip/hip_bf16.h>

#define NN 50000
#define EE 800000
#define DD 128
#define CB 196      // coarse buckets of 256 nodes (196*256 = 50176)
#define NFB 1563    // fine buckets of 32 nodes (mega grid)
#define EBLK 2048
#define NEBK 391    // ceil(EE/EBLK)
#define XSB 3125    // xs-scale blocks: 3125*256 = 800000 = NN*16 bf16x8 items
#define SSZ 5120    // srcU16 LDS staging capacity per coarse bucket (avg 4082, sigma 64)

typedef __attribute__((ext_vector_type(8))) short bf16x8;
typedef __attribute__((ext_vector_type(4))) float f32x4;

static __device__ __forceinline__ unsigned short f2bf(float f) {
  union { float f; unsigned u; } v; v.f = f;
  unsigned r = v.u + 0x7FFFu + ((v.u >> 16) & 1u);
  return (unsigned short)(r >> 16);
}
static __device__ __forceinline__ float bf2f(unsigned short h) {
  union { unsigned u; float f; } v; v.u = ((unsigned)h) << 16;
  return v.f;
}

// blocks [0,391): per-chunk coarse histogram of dst>>8 -> hist[chunk][cb] (plain stores).
// blocks [391,423): Wt[n][k] bf16 combined (k<128: W_gcn, k>=128: W_lin).
// blocks [423,1986): x -> bf16 xb (unscaled).
__global__ __launch_bounds__(256) void k_p0(
    const int* __restrict__ dst, int* __restrict__ hist,
    const float* __restrict__ Wg, const float* __restrict__ Wl,
    unsigned short* __restrict__ Wt, const float4* __restrict__ x4,
    ushort4* __restrict__ xb4) {
  int b = blockIdx.x, t = threadIdx.x;
  if (b < NEBK) {
    __shared__ int cnt[CB];
    for (int i = t; i < CB; i += 256) cnt[i] = 0;
    __syncthreads();
    int e0 = b * EBLK;
    for (int i = t; i < EBLK; i += 256) {
      int e = e0 + i;
      if (e < EE) atomicAdd(&cnt[dst[e] >> 8], 1);
    }
    __syncthreads();
    for (int i = t; i < CB; i += 256) hist[b * CB + i] = cnt[i];
  } else if (b < NEBK + 32) {
    for (int i = (b - NEBK) * 256 + t; i < DD * 256; i += 32 * 256) {
      int n = i >> 8, k = i & 255;
      float v = (k < 128) ? Wg[k * DD + n] : Wl[(k - 128) * DD + n];
      Wt[i] = f2bf(v);
    }
  } else {
    int base = (b - NEBK - 32) * 1024 + t;
#pragma unroll
    for (int k = 0; k < 4; k++) {
      int i = base + k * 256;
      if (i < NN * 32) {
        float4 v = x4[i];
        ushort4 o;
        o.x = f2bf(v.x); o.y = f2bf(v.y); o.z = f2bf(v.z); o.w = f2bf(v.w);
        xb4[i] = o;
      }
    }
  }
}

// One block per edge chunk: counting-sort the chunk's edges into coarse-bucket
// runs of the global pairs array. All bases self-computed from hist — NO global
// atomics. LDS-sorted staging -> coalesced global writes.
// Record: src(16b) | dlocal(8b)<<16 | coarse(8b)<<24.
__global__ __launch_bounds__(512) void k_scatter(
    const int* __restrict__ src, const int* __restrict__ dst,
    const int* __restrict__ hist, int* __restrict__ coarseTot,
    unsigned int* __restrict__ pairs) {
  __shared__ unsigned int rec[EBLK];     // 8 KB
  __shared__ unsigned int sorted[EBLK];  // 8 KB
  __shared__ int tot[CB], chunk[CB], own[CB], cur[CB], gofs[CB];
  __shared__ int sc[256];
  int blk = blockIdx.x, t = threadIdx.x;
  int e0 = blk * EBLK;
  int vcnt = EE - e0; if (vcnt > EBLK) vcnt = EBLK;
  // stage records in LDS (chunk order)
  for (int i = t; i < vcnt; i += 512) {
    int d = dst[e0 + i], s = src[e0 + i];
    rec[i] = (unsigned int)s | ((unsigned int)(d & 255) << 16) |
             ((unsigned int)(d >> 8) << 24);
  }
  // column sums over hist: total per bucket, prefix below this chunk, own count
  if (t < CB) {
    int to = 0, ch = 0, ow = 0;
    for (int b2 = 0; b2 < NEBK; ++b2) {
      int v = hist[b2 * CB + t];
      to += v;
      ch += (b2 < blk) ? v : 0;
      ow = (b2 == blk) ? v : ow;
    }
    tot[t] = to; chunk[t] = ch; own[t] = ow;
    if (blk == 0) coarseTot[t] = to;
  }
  __syncthreads();
  // scan 1: exclusive prefix of bucket totals -> global bucket base
  if (t < 256) sc[t] = (t < CB) ? tot[t] : 0;
  for (int off = 1; off < 256; off <<= 1) {
    __syncthreads();
    int tmp = (t < 256 && t >= off) ? sc[t - off] : 0;
    __syncthreads();
    if (t < 256 && t >= off) sc[t] += tmp;
  }
  __syncthreads();
  if (t < CB) gofs[t] = (sc[t] - tot[t]) + chunk[t];  // this chunk's run start
  __syncthreads();
  // scan 2: exclusive prefix of own counts -> local sorted offsets
  if (t < 256) sc[t] = (t < CB) ? own[t] : 0;
  for (int off = 1; off < 256; off <<= 1) {
    __syncthreads();
    int tmp = (t < 256 && t >= off) ? sc[t - off] : 0;
    __syncthreads();
    if (t < 256 && t >= off) sc[t] += tmp;
  }
  __syncthreads();
  if (t < CB) {
    int lo = sc[t] - own[t];
    cur[t] = lo;
    gofs[t] -= lo;   // pairs addr for sorted slot i of bucket cb: gofs[cb] + i
  }
  __syncthreads();
  // local counting-sort into LDS
  for (int i = t; i < vcnt; i += 512) {
    unsigned int r = rec[i];
    int cb = r >> 24;
    int p = atomicAdd(&cur[cb], 1);
    sorted[p] = r;
  }
  __syncthreads();
  // coalesced write-out (bucket runs are contiguous in both LDS and global)
  for (int i = t; i < vcnt; i += 512) {
    unsigned int r = sorted[i];
    pairs[gofs[r >> 24] + i] = r;
  }
}

// One block per coarse bucket: self-computed start, LDS histogram from pairs,
// scan -> deg/dinv/rowStart, LDS-staged sort of src -> coalesced srcU16 write.
__global__ __launch_bounds__(512) void k_p1b(
    const unsigned int* __restrict__ pairs, const int* __restrict__ coarseTot,
    int* __restrict__ deg, float* __restrict__ dinv, int* __restrict__ rowStart,
    unsigned short* __restrict__ srcU16) {
  __shared__ int ldeg[256], lscan[256], lcur[256];
  __shared__ int wsum[8];
  __shared__ unsigned short ssrc[SSZ];  // 10 KB
  int b = blockIdx.x, t = threadIdx.x;
  int n0 = b << 8;
  int nloc = NN - n0; if (nloc > 256) nloc = 256;
  int partial = 0;
  for (int i = t; i < b; i += 512) partial += coarseTot[i];
#pragma unroll
  for (int off = 32; off > 0; off >>= 1) partial += __shfl_xor(partial, off);
  if ((t & 63) == 0) wsum[t >> 6] = partial;
  if (t < 256) ldeg[t] = 0;
  __syncthreads();
  int start = wsum[0] + wsum[1] + wsum[2] + wsum[3] +
              wsum[4] + wsum[5] + wsum[6] + wsum[7];
  int cnt = coarseTot[b];
  for (int i = t; i < cnt; i += 512)
    atomicAdd(&ldeg[(pairs[start + i] >> 16) & 255], 1);
  __syncthreads();
  int dg = (t < 256) ? ldeg[t] : 0;
  if (t < 256) lscan[t] = dg;
  for (int off = 1; off < 256; off <<= 1) {
    __syncthreads();
    int tmp = (t < 256 && t >= off) ? lscan[t - off] : 0;
    __syncthreads();
    if (t < 256 && t >= off) lscan[t] += tmp;
  }
  __syncthreads();
  bool useStage = (cnt <= SSZ);
  if (t < 256) {
    int lofs = lscan[t] - dg;        // local (bucket-relative) row start
    lcur[t] = lofs;
    if (t < nloc) {
      deg[n0 + t] = dg;
      dinv[n0 + t] = rsqrtf((float)(dg + 1));
      rowStart[n0 + t] = start + lofs;
    }
  }
  __syncthreads();
  for (int i = t; i < cnt; i += 512) {
    unsigned int pr = pairs[start + i];
    int pos = atomicAdd(&lcur[(pr >> 16) & 255], 1);
    unsigned short v = (unsigned short)(pr & 0xFFFFu);
    if (useStage) ssrc[pos] = v;
    else          srcU16[start + pos] = v;
  }
  if (useStage) {
    __syncthreads();
    for (int i = t; i < cnt; i += 512) srcU16[start + i] = ssrc[i];
  }
}

// Streaming, full occupancy: xs = dinv * xb.
__global__ __launch_bounds__(256) void k_xs(
    const unsigned short* __restrict__ xb, const float* __restrict__ dinv,
    unsigned short* __restrict__ xs) {
  int i = blockIdx.x * 256 + threadIdx.x;  // 3125*256 == NN*16 exactly
  int row = i >> 4;
  float di = dinv[row];
  bf16x8 v = *(const bf16x8*)(xb + (size_t)i * 8);
  bf16x8 o;
#pragma unroll
  for (int k = 0; k < 8; k++) o[k] = (short)f2bf(bf2f((unsigned short)v[k]) * di);
  *(bf16x8*)(xs + (size_t)i * 8) = o;
}

// Gather a node's CSR range into acc[8] (lane slice r*8), 8 rows in flight.
static __device__ __forceinline__ void gather16(
    const unsigned short* __restrict__ xs, const unsigned short* __restrict__ srcU16,
    int js, int cnt, int r, int srcLaneBase, float* acc) {
  for (int base = 0; base < cnt; base += 16) {
    int idx = (base + r < cnt) ? (int)srcU16[js + base + r] : 0;
    int m = cnt - base; if (m > 16) m = 16;
    int j = 0;
    for (; j + 8 <= m; j += 8) {
      int s0 = __shfl(idx, srcLaneBase + j);
      int s1 = __shfl(idx, srcLaneBase + j + 1);
      int s2 = __shfl(idx, srcLaneBase + j + 2);
      int s3 = __shfl(idx, srcLaneBase + j + 3);
      int s4 = __shfl(idx, srcLaneBase + j + 4);
      int s5 = __shfl(idx, srcLaneBase + j + 5);
      int s6 = __shfl(idx, srcLaneBase + j + 6);
      int s7 = __shfl(idx, srcLaneBase + j + 7);
      bf16x8 v0 = *(const bf16x8*)(xs + (size_t)s0 * DD + r * 8);
      bf16x8 v1 = *(const bf16x8*)(xs + (size_t)s1 * DD + r * 8);
      bf16x8 v2 = *(const bf16x8*)(xs + (size_t)s2 * DD + r * 8);
      bf16x8 v3 = *(const bf16x8*)(xs + (size_t)s3 * DD + r * 8);
      bf16x8 v4 = *(const bf16x8*)(xs + (size_t)s4 * DD + r * 8);
      bf16x8 v5 = *(const bf16x8*)(xs + (size_t)s5 * DD + r * 8);
      bf16x8 v6 = *(const bf16x8*)(xs + (size_t)s6 * DD + r * 8);
      bf16x8 v7 = *(const bf16x8*)(xs + (size_t)s7 * DD + r * 8);
#pragma unroll
      for (int k = 0; k < 8; k++) acc[k] += bf2f((unsigned short)v0[k]);
#pragma unroll
      for (int k = 0; k < 8; k++) acc[k] += bf2f((unsigned short)v1[k]);
#pragma unroll
      for (int k = 0; k < 8; k++) acc[k] += bf2f((unsigned short)v2[k]);
#pragma unroll
      for (int k = 0; k < 8; k++) acc[k] += bf2f((unsigned short)v3[k]);
#pragma unroll
      for (int k = 0; k < 8; k++) acc[k] += bf2f((unsigned short)v4[k]);
#pragma unroll
      for (int k = 0; k < 8; k++) acc[k] += bf2f((unsigned short)v5[k]);
#pragma unroll
      for (int k = 0; k < 8; k++) acc[k] += bf2f((unsigned short)v6[k]);
#pragma unroll
      for (int k = 0; k < 8; k++) acc[k] += bf2f((unsigned short)v7[k]);
    }
    for (; j < m; j++) {
      int s = __shfl(idx, srcLaneBase + j);
      bf16x8 v = *(const bf16x8*)(xs + (size_t)s * DD + r * 8);
#pragma unroll
      for (int k = 0; k < 8; k++) acc[k] += bf2f((unsigned short)v[k]);
    }
  }
}

// One block per 32-node bucket, 512 threads: 32 groups x 1 node gather,
// then waves 0-1 run the MFMA [agg|x]@[Wg;Wl] + bias + LayerNorm epilogue.
__global__ __launch_bounds__(512) void k_mega4(
    const unsigned short* __restrict__ xs, const unsigned short* __restrict__ xb,
    const int* __restrict__ rowStart, const int* __restrict__ deg,
    const unsigned short* __restrict__ srcU16, const float* __restrict__ dinv,
    const unsigned short* __restrict__ Wt, const float* __restrict__ bgcn,
    const float* __restrict__ lnw, const float* __restrict__ lnb,
    float* __restrict__ out) {
  __shared__ unsigned short abuf[32 * 136];  // 8.7 KB
  int b = blockIdx.x, t = threadIdx.x;
  int n0 = b * 32;
  int g = t >> 4, r = t & 15;
  int lane = t & 63;
  int srcLaneBase = lane & 48;
  int node = n0 + g;
  bool valid = (node < NN);
  int nc = valid ? node : (NN - 1);
  float acc[8];
  {  // self-loop init from pre-scaled xs
    bf16x8 va = *(const bf16x8*)(xs + (size_t)nc * DD + r * 8);
#pragma unroll
    for (int k = 0; k < 8; k++) acc[k] = bf2f((unsigned short)va[k]);
  }
  int js = valid ? rowStart[nc] : 0;
  int cnt = valid ? deg[nc] : 0;
  gather16(xs, srcU16, js, cnt, r, srcLaneBase, acc);
  {
    float d = dinv[nc];
    bf16x8 o;
#pragma unroll
    for (int k = 0; k < 8; k++) o[k] = valid ? (short)f2bf(acc[k] * d) : (short)0;
    *(bf16x8*)&abuf[g * 136 + r * 8] = o;
  }
  __syncthreads();
  if (t < 128) {  // waves 0,1: two 16-row MFMA tiles + fused LayerNorm
    int w = t >> 6, lane2 = t & 63;
    int quad = lane2 >> 4, rr = lane2 & 15;
    int mloc = w * 16 + rr;
    int rowA = n0 + mloc; int rc = (rowA < NN) ? rowA : (NN - 1);
    f32x4 zero = {0.f, 0.f, 0.f, 0.f};
    f32x4 macc[8];
#pragma unroll
    for (int i = 0; i < 8; i++) macc[i] = zero;
#pragma unroll
    for (int ks = 0; ks < 8; ks++) {
      bf16x8 a;
      if (ks < 4) a = *(const bf16x8*)&abuf[mloc * 136 + ks * 32 + quad * 8];
      else        a = *(const bf16x8*)(xb + (size_t)rc * DD + (ks - 4) * 32 + quad * 8);
#pragma unroll
      for (int nt = 0; nt < 8; nt++) {
        bf16x8 bb = *(const bf16x8*)(Wt + (size_t)(nt * 16 + rr) * 256 + ks * 32 + quad * 8);
        macc[nt] = __builtin_amdgcn_mfma_f32_16x16x32_bf16(a, bb, macc[nt], 0, 0, 0);
      }
    }
    float bg[8], lw[8], lb[8];
#pragma unroll
    for (int nt = 0; nt < 8; nt++) {
      int col = nt * 16 + rr;
      bg[nt] = bgcn[col] + 1e-6f;
      lw[nt] = lnw[col];
      lb[nt] = lnb[col];
    }
#pragma unroll
    for (int reg = 0; reg < 4; reg++) {
      float y[8];
      float s1 = 0.f, s2 = 0.f;
#pragma unroll
      for (int nt = 0; nt < 8; nt++) {
        y[nt] = macc[nt][reg] + bg[nt];
        s1 += y[nt];
        s2 += y[nt] * y[nt];
      }
#pragma unroll
      for (int off = 1; off < 16; off <<= 1) {
        s1 += __shfl_xor(s1, off);
        s2 += __shfl_xor(s2, off);
      }
      float mu = s1 * (1.0f / 128.0f);
      float var = s2 * (1.0f / 128.0f) - mu * mu;
      float inv = rsqrtf(var + 1e-5f);
      int row = n0 + w * 16 + quad * 4 + reg;
      if (row < NN) {
#pragma unroll
        for (int nt = 0; nt < 8; nt++) {
          out[(size_t)row * DD + nt * 16 + rr] = (y[nt] - mu) * inv * lw[nt] + lb[nt];
        }
      }
    }
  }
}

extern "C" void kernel_launch(void* const* d_in, const int* in_sizes, int n_in,
                              void* d_out, int out_size, void* d_ws, size_t ws_size,
                              hipStream_t stream) {
  const int* adj = (const int*)d_in[0];
  const float* x = (const float*)d_in[1];
  const float* Wg = (const float*)d_in[2];
  const float* bg = (const float*)d_in[3];
  const float* Wl = (const float*)d_in[4];
  const float* lw = (const float*)d_in[5];
  const float* lb = (const float*)d_in[6];
  const int* srcp = adj;
  const int* dstp = adj + EE;
  float* out = (float*)d_out;

  char* ws = (char*)d_ws;
  size_t off = 0;
  auto alloc = [&](size_t bytes) -> void* {
    void* p = ws + off;
    off += (bytes + 255) & ~(size_t)255;
    return p;
  };
  int* hist = (int*)alloc((size_t)NEBK * CB * 4);
  int* coarseTot = (int*)alloc((size_t)256 * 4);
  unsigned int* pairs = (unsigned int*)alloc((size_t)EE * 4);
  unsigned short* srcU16 = (unsigned short*)alloc((size_t)EE * 2);
  int* deg = (int*)alloc((size_t)NN * 4);
  float* dinv = (float*)alloc((size_t)NN * 4);
  int* rowStart = (int*)alloc((size_t)NN * 4);
  unsigned short* xb = (unsigned short*)alloc((size_t)NN * DD * 2);
  unsigned short* xs = (unsigned short*)alloc((size_t)NN * DD * 2);
  unsigned short* Wt = (unsigned short*)alloc((size_t)DD * 256 * 2);
  (void)ws_size; (void)in_sizes; (void)n_in; (void)out_size;

  // no memsets: hist fully written by k_p0; everything else fully written.
  k_p0<<<NEBK + 32 + 1563, 256, 0, stream>>>(dstp, hist, Wg, Wl, Wt,
                                             (const float4*)x, (ushort4*)xb);
  k_scatter<<<NEBK, 512, 0, stream>>>(srcp, dstp, hist, coarseTot, pairs);
  k_p1b<<<CB, 512, 0, stream>>>(pairs, coarseTot, deg, dinv, rowStart, srcU16);
  k_xs<<<XSB, 256, 0, stream>>>(xb, dinv, xs);
  k_mega4<<<NFB, 512, 0, stream>>>(xs, xb, rowStart, deg, srcU16, dinv, Wt,
                                   bg, lw, lb, out);
}

// Round 4
// 187.074 us; speedup vs baseline: 1.2838x; 1.0699x over previous
//
#include <hip/hip_runtime.h>
#include <hip/hip_bf16.h>

#define NN 50000
#define EE 800000
#define DD 128
#define CB 196      // coarse buckets of 256 nodes (196*256 = 50176)
#define NFB 1563    // fine buckets of 32 nodes (mega grid)
#define EBLK 2048
#define NEBK 391    // ceil(EE/EBLK)
#define HST 392     // hist row stride (NEBK padded to multiple of 4)

typedef __attribute__((ext_vector_type(8))) short bf16x8;
typedef __attribute__((ext_vector_type(4))) float f32x4;

static __device__ __forceinline__ unsigned short f2bf(float f) {
  union { float f; unsigned u; } v; v.f = f;
  unsigned r = v.u + 0x7FFFu + ((v.u >> 16) & 1u);
  return (unsigned short)(r >> 16);
}
static __device__ __forceinline__ float bf2f(unsigned short h) {
  union { unsigned u; float f; } v; v.u = ((unsigned)h) << 16;
  return v.f;
}

// blocks [0,391): per-chunk coarse histogram of dst>>8 -> hist[cb][chunk] (TRANSPOSED).
// blocks [391,423): Wt[n][k] bf16 combined (k<128: W_gcn, k>=128: W_lin).
// blocks [423,1986): x -> bf16 xb (unscaled).
__global__ __launch_bounds__(256) void k_p0(
    const int* __restrict__ dst, int* __restrict__ hist,
    const float* __restrict__ Wg, const float* __restrict__ Wl,
    unsigned short* __restrict__ Wt, const float4* __restrict__ x4,
    ushort4* __restrict__ xb4) {
  int b = blockIdx.x, t = threadIdx.x;
  if (b < NEBK) {
    __shared__ int cnt[CB];
    for (int i = t; i < CB; i += 256) cnt[i] = 0;
    __syncthreads();
    int e0 = b * EBLK;
    for (int i = t; i < EBLK; i += 256) {
      int e = e0 + i;
      if (e < EE) atomicAdd(&cnt[dst[e] >> 8], 1);
    }
    __syncthreads();
    if (t < CB) {
      hist[t * HST + b] = cnt[t];          // transposed: bucket-major rows
      if (b == 0) hist[t * HST + (HST - 1)] = 0;  // zero the pad column
    }
  } else if (b < NEBK + 32) {
    for (int i = (b - NEBK) * 256 + t; i < DD * 256; i += 32 * 256) {
      int n = i >> 8, k = i & 255;
      float v = (k < 128) ? Wg[k * DD + n] : Wl[(k - 128) * DD + n];
      Wt[i] = f2bf(v);
    }
  } else {
    int base = (b - NEBK - 32) * 1024 + t;
#pragma unroll
    for (int k = 0; k < 4; k++) {
      int i = base + k * 256;
      if (i < NN * 32) {
        float4 v = x4[i];
        ushort4 o;
        o.x = f2bf(v.x); o.y = f2bf(v.y); o.z = f2bf(v.z); o.w = f2bf(v.w);
        xb4[i] = o;
      }
    }
  }
}

// One block per edge chunk: counting-sort the chunk's edges into coarse-bucket
// runs of the global pairs array. Bases self-computed from transposed hist via
// contiguous uint4 row reads (2 threads per bucket). NO global atomics.
// Record: src(16b) | dlocal(8b)<<16 | coarse(8b)<<24.
__global__ __launch_bounds__(512) void k_scatter(
    const int* __restrict__ src, const int* __restrict__ dst,
    const int* __restrict__ hist, int* __restrict__ bucketBase,
    int* __restrict__ bucketTot, unsigned int* __restrict__ pairs) {
  __shared__ unsigned int rec[EBLK];     // 8 KB
  __shared__ unsigned int sorted[EBLK];  // 8 KB
  __shared__ int sTo[2][CB], sCh[2][CB], sOw[2][CB];  // 4.7 KB
  __shared__ unsigned int sc[256];
  __shared__ int cur[CB], gofs[CB];
  int blk = blockIdx.x, t = threadIdx.x;
  int e0 = blk * EBLK;
  int vcnt = EE - e0; if (vcnt > EBLK) vcnt = EBLK;
  // stage records in LDS (chunk order); same thread later re-reads its own slots
  for (int i = t; i < vcnt; i += 512) {
    int d = dst[e0 + i], s = src[e0 + i];
    rec[i] = (unsigned int)s | ((unsigned int)(d & 255) << 16) |
             ((unsigned int)(d >> 8) << 24);
  }
  // vectorized column sums over transposed hist rows: thread (q, half)
  int q = t & 255, h = t >> 8;
  if (q < CB) {
    const uint4* hp = (const uint4*)(hist + (size_t)q * HST + h * (HST / 2));
    int cb0 = h * (HST / 2);
    int to = 0, ch = 0, ow = 0;
#pragma unroll 7
    for (int v = 0; v < HST / 8; ++v) {   // 49 uint4 per half
      uint4 hv = hp[v];
      int c = cb0 + v * 4;
      int a0 = (int)hv.x, a1 = (int)hv.y, a2 = (int)hv.z, a3 = (int)hv.w;
      to += a0 + a1 + a2 + a3;
      ch += (c + 0 < blk ? a0 : 0) + (c + 1 < blk ? a1 : 0) +
            (c + 2 < blk ? a2 : 0) + (c + 3 < blk ? a3 : 0);
      ow += (c + 0 == blk ? a0 : 0) + (c + 1 == blk ? a1 : 0) +
            (c + 2 == blk ? a2 : 0) + (c + 3 == blk ? a3 : 0);
    }
    sTo[h][q] = to; sCh[h][q] = ch; sOw[h][q] = ow;
  }
  __syncthreads();
  int totv = 0, chpv = 0, ownv = 0;
  if (t < CB) {
    totv = sTo[0][t] + sTo[1][t];
    chpv = sCh[0][t] + sCh[1][t];
    ownv = sOw[0][t] + sOw[1][t];
  }
  // single packed scan: (tot<<12)|own  (tot-sum <= 800K < 2^20, own-sum <= 2048)
  if (t < 256) sc[t] = (t < CB) ? (((unsigned)totv << 12) | (unsigned)ownv) : 0u;
  for (int off = 1; off < 256; off <<= 1) {
    __syncthreads();
    unsigned tmp = (t < 256 && t >= off) ? sc[t - off] : 0u;
    __syncthreads();
    if (t < 256 && t >= off) sc[t] += tmp;
  }
  __syncthreads();
  if (t < CB) {
    unsigned v = sc[t];
    int incT = (int)(v >> 12), incO = (int)(v & 4095u);
    int gb = incT - totv;     // bucket global base
    int lo = incO - ownv;     // local sorted base within this chunk
    cur[t] = lo;
    gofs[t] = gb + chpv - lo; // pairs addr of sorted slot i: gofs[cb] + i
    if (blk == 0) { bucketBase[t] = gb; bucketTot[t] = totv; }
  }
  __syncthreads();
  // local counting-sort into LDS (rec[i] re-read by its own writer thread)
  for (int i = t; i < vcnt; i += 512) {
    unsigned int r = rec[i];
    int p = atomicAdd(&cur[r >> 24], 1);
    sorted[p] = r;
  }
  __syncthreads();
  // coalesced write-out (bucket runs contiguous in both LDS and global)
  for (int i = t; i < vcnt; i += 512) {
    unsigned int r = sorted[i];
    pairs[gofs[r >> 24] + i] = r;
  }
}

// One block per coarse bucket: fine histogram from pairs, scan ->
// deg/dinv/rowStart, scatter src -> srcU16, and xs = dinv*xb fold.
__global__ __launch_bounds__(512) void k_p1b(
    const unsigned int* __restrict__ pairs, const int* __restrict__ bucketBase,
    const int* __restrict__ bucketTot, const unsigned short* __restrict__ xb,
    int* __restrict__ deg, float* __restrict__ dinv, int* __restrict__ rowStart,
    unsigned short* __restrict__ srcU16, unsigned short* __restrict__ xs) {
  __shared__ int ldeg[256], lscan[256], lcur[256];
  __shared__ float ldinvs[256];
  int b = blockIdx.x, t = threadIdx.x;
  int n0 = b << 8;
  int nloc = NN - n0; if (nloc > 256) nloc = 256;
  int start = bucketBase[b];
  int cnt = bucketTot[b];
  if (t < 256) ldeg[t] = 0;
  __syncthreads();
  for (int i = t; i < cnt; i += 512)
    atomicAdd(&ldeg[(pairs[start + i] >> 16) & 255], 1);
  __syncthreads();
  int dg = (t < 256) ? ldeg[t] : 0;
  if (t < 256) lscan[t] = dg;
  for (int off = 1; off < 256; off <<= 1) {
    __syncthreads();
    int tmp = (t < 256 && t >= off) ? lscan[t - off] : 0;
    __syncthreads();
    if (t < 256 && t >= off) lscan[t] += tmp;
  }
  __syncthreads();
  if (t < 256) {
    int rs = start + lscan[t] - dg;
    lcur[t] = rs;
    float di = rsqrtf((float)(dg + 1));
    ldinvs[t] = di;
    if (t < nloc) { deg[n0 + t] = dg; dinv[n0 + t] = di; rowStart[n0 + t] = rs; }
  }
  __syncthreads();
  for (int i = t; i < cnt; i += 512) {
    unsigned int pr = pairs[start + i];
    int pos = atomicAdd(&lcur[(pr >> 16) & 255], 1);
    srcU16[pos] = (unsigned short)(pr & 0xFFFFu);
  }
  // xs fold: scale this bucket's rows (independent of scatter above)
  for (int i = t; i < nloc * 16; i += 512) {
    int rr = i >> 4, qq = i & 15;
    bf16x8 v = *(const bf16x8*)(xb + (size_t)(n0 + rr) * DD + qq * 8);
    float di = ldinvs[rr];
    bf16x8 o;
#pragma unroll
    for (int k = 0; k < 8; k++) o[k] = (short)f2bf(bf2f((unsigned short)v[k]) * di);
    *(bf16x8*)(xs + (size_t)(n0 + rr) * DD + qq * 8) = o;
  }
}

// Gather a node's CSR range into acc[8] (lane slice r*8), 8 rows in flight.
static __device__ __forceinline__ void gather16(
    const unsigned short* __restrict__ xs, const unsigned short* __restrict__ srcU16,
    int js, int cnt, int r, int srcLaneBase, float* acc) {
  for (int base = 0; base < cnt; base += 16) {
    int idx = (base + r < cnt) ? (int)srcU16[js + base + r] : 0;
    int m = cnt - base; if (m > 16) m = 16;
    int j = 0;
    for (; j + 8 <= m; j += 8) {
      int s0 = __shfl(idx, srcLaneBase + j);
      int s1 = __shfl(idx, srcLaneBase + j + 1);
      int s2 = __shfl(idx, srcLaneBase + j + 2);
      int s3 = __shfl(idx, srcLaneBase + j + 3);
      int s4 = __shfl(idx, srcLaneBase + j + 4);
      int s5 = __shfl(idx, srcLaneBase + j + 5);
      int s6 = __shfl(idx, srcLaneBase + j + 6);
      int s7 = __shfl(idx, srcLaneBase + j + 7);
      bf16x8 v0 = *(const bf16x8*)(xs + (size_t)s0 * DD + r * 8);
      bf16x8 v1 = *(const bf16x8*)(xs + (size_t)s1 * DD + r * 8);
      bf16x8 v2 = *(const bf16x8*)(xs + (size_t)s2 * DD + r * 8);
      bf16x8 v3 = *(const bf16x8*)(xs + (size_t)s3 * DD + r * 8);
      bf16x8 v4 = *(const bf16x8*)(xs + (size_t)s4 * DD + r * 8);
      bf16x8 v5 = *(const bf16x8*)(xs + (size_t)s5 * DD + r * 8);
      bf16x8 v6 = *(const bf16x8*)(xs + (size_t)s6 * DD + r * 8);
      bf16x8 v7 = *(const bf16x8*)(xs + (size_t)s7 * DD + r * 8);
#pragma unroll
      for (int k = 0; k < 8; k++) acc[k] += bf2f((unsigned short)v0[k]);
#pragma unroll
      for (int k = 0; k < 8; k++) acc[k] += bf2f((unsigned short)v1[k]);
#pragma unroll
      for (int k = 0; k < 8; k++) acc[k] += bf2f((unsigned short)v2[k]);
#pragma unroll
      for (int k = 0; k < 8; k++) acc[k] += bf2f((unsigned short)v3[k]);
#pragma unroll
      for (int k = 0; k < 8; k++) acc[k] += bf2f((unsigned short)v4[k]);
#pragma unroll
      for (int k = 0; k < 8; k++) acc[k] += bf2f((unsigned short)v5[k]);
#pragma unroll
      for (int k = 0; k < 8; k++) acc[k] += bf2f((unsigned short)v6[k]);
#pragma unroll
      for (int k = 0; k < 8; k++) acc[k] += bf2f((unsigned short)v7[k]);
    }
    for (; j < m; j++) {
      int s = __shfl(idx, srcLaneBase + j);
      bf16x8 v = *(const bf16x8*)(xs + (size_t)s * DD + r * 8);
#pragma unroll
      for (int k = 0; k < 8; k++) acc[k] += bf2f((unsigned short)v[k]);
    }
  }
}

// One block per 32-node bucket, 512 threads: 32 groups x 1 node gather,
// then waves 0-1 run the MFMA [agg|x]@[Wg;Wl] + bias + LayerNorm epilogue.
__global__ __launch_bounds__(512) void k_mega4(
    const unsigned short* __restrict__ xs, const unsigned short* __restrict__ xb,
    const int* __restrict__ rowStart, const int* __restrict__ deg,
    const unsigned short* __restrict__ srcU16, const float* __restrict__ dinv,
    const unsigned short* __restrict__ Wt, const float* __restrict__ bgcn,
    const float* __restrict__ lnw, const float* __restrict__ lnb,
    float* __restrict__ out) {
  __shared__ unsigned short abuf[32 * 136];  // 8.7 KB
  int b = blockIdx.x, t = threadIdx.x;
  int n0 = b * 32;
  int g = t >> 4, r = t & 15;
  int lane = t & 63;
  int srcLaneBase = lane & 48;
  int node = n0 + g;
  bool valid = (node < NN);
  int nc = valid ? node : (NN - 1);
  float acc[8];
  {  // self-loop init from pre-scaled xs
    bf16x8 va = *(const bf16x8*)(xs + (size_t)nc * DD + r * 8);
#pragma unroll
    for (int k = 0; k < 8; k++) acc[k] = bf2f((unsigned short)va[k]);
  }
  int js = valid ? rowStart[nc] : 0;
  int cnt = valid ? deg[nc] : 0;
  gather16(xs, srcU16, js, cnt, r, srcLaneBase, acc);
  {
    float d = dinv[nc];
    bf16x8 o;
#pragma unroll
    for (int k = 0; k < 8; k++) o[k] = valid ? (short)f2bf(acc[k] * d) : (short)0;
    *(bf16x8*)&abuf[g * 136 + r * 8] = o;
  }
  __syncthreads();
  if (t < 128) {  // waves 0,1: two 16-row MFMA tiles + fused LayerNorm
    int w = t >> 6, lane2 = t & 63;
    int quad = lane2 >> 4, rr = lane2 & 15;
    int mloc = w * 16 + rr;
    int rowA = n0 + mloc; int rc = (rowA < NN) ? rowA : (NN - 1);
    f32x4 zero = {0.f, 0.f, 0.f, 0.f};
    f32x4 macc[8];
#pragma unroll
    for (int i = 0; i < 8; i++) macc[i] = zero;
#pragma unroll
    for (int ks = 0; ks < 8; ks++) {
      bf16x8 a;
      if (ks < 4) a = *(const bf16x8*)&abuf[mloc * 136 + ks * 32 + quad * 8];
      else        a = *(const bf16x8*)(xb + (size_t)rc * DD + (ks - 4) * 32 + quad * 8);
#pragma unroll
      for (int nt = 0; nt < 8; nt++) {
        bf16x8 bb = *(const bf16x8*)(Wt + (size_t)(nt * 16 + rr) * 256 + ks * 32 + quad * 8);
        macc[nt] = __builtin_amdgcn_mfma_f32_16x16x32_bf16(a, bb, macc[nt], 0, 0, 0);
      }
    }
    float bg[8], lw[8], lb[8];
#pragma unroll
    for (int nt = 0; nt < 8; nt++) {
      int col = nt * 16 + rr;
      bg[nt] = bgcn[col] + 1e-6f;
      lw[nt] = lnw[col];
      lb[nt] = lnb[col];
    }
#pragma unroll
    for (int reg = 0; reg < 4; reg++) {
      float y[8];
      float s1 = 0.f, s2 = 0.f;
#pragma unroll
      for (int nt = 0; nt < 8; nt++) {
        y[nt] = macc[nt][reg] + bg[nt];
        s1 += y[nt];
        s2 += y[nt] * y[nt];
      }
#pragma unroll
      for (int off = 1; off < 16; off <<= 1) {
        s1 += __shfl_xor(s1, off);
        s2 += __shfl_xor(s2, off);
      }
      float mu = s1 * (1.0f / 128.0f);
      float var = s2 * (1.0f / 128.0f) - mu * mu;
      float inv = rsqrtf(var + 1e-5f);
      int row = n0 + w * 16 + quad * 4 + reg;
      if (row < NN) {
#pragma unroll
        for (int nt = 0; nt < 8; nt++) {
          out[(size_t)row * DD + nt * 16 + rr] = (y[nt] - mu) * inv * lw[nt] + lb[nt];
        }
      }
    }
  }
}

extern "C" void kernel_launch(void* const* d_in, const int* in_sizes, int n_in,
                              void* d_out, int out_size, void* d_ws, size_t ws_size,
                              hipStream_t stream) {
  const int* adj = (const int*)d_in[0];
  const float* x = (const float*)d_in[1];
  const float* Wg = (const float*)d_in[2];
  const float* bg = (const float*)d_in[3];
  const float* Wl = (const float*)d_in[4];
  const float* lw = (const float*)d_in[5];
  const float* lb = (const float*)d_in[6];
  const int* srcp = adj;
  const int* dstp = adj + EE;
  float* out = (float*)d_out;

  char* ws = (char*)d_ws;
  size_t off = 0;
  auto alloc = [&](size_t bytes) -> void* {
    void* p = ws + off;
    off += (bytes + 255) & ~(size_t)255;
    return p;
  };
  int* hist = (int*)alloc((size_t)CB * HST * 4);     // transposed, padded
  int* bucketBase = (int*)alloc((size_t)256 * 4);
  int* bucketTot = (int*)alloc((size_t)256 * 4);
  unsigned int* pairs = (unsigned int*)alloc((size_t)EE * 4);
  unsigned short* srcU16 = (unsigned short*)alloc((size_t)EE * 2);
  int* deg = (int*)alloc((size_t)NN * 4);
  float* dinv = (float*)alloc((size_t)NN * 4);
  int* rowStart = (int*)alloc((size_t)NN * 4);
  unsigned short* xb = (unsigned short*)alloc((size_t)NN * DD * 2);
  unsigned short* xs = (unsigned short*)alloc((size_t)NN * DD * 2);
  unsigned short* Wt = (unsigned short*)alloc((size_t)DD * 256 * 2);
  (void)ws_size; (void)in_sizes; (void)n_in; (void)out_size;

  // no memsets: hist columns (incl. pad) fully written by k_p0.
  k_p0<<<NEBK + 32 + 1563, 256, 0, stream>>>(dstp, hist, Wg, Wl, Wt,
                                             (const float4*)x, (ushort4*)xb);
  k_scatter<<<NEBK, 512, 0, stream>>>(srcp, dstp, hist, bucketBase, bucketTot,
                                      pairs);
  k_p1b<<<CB, 512, 0, stream>>>(pairs, bucketBase, bucketTot, xb, deg, dinv,
                                rowStart, srcU16, xs);
  k_mega4<<<NFB, 512, 0, stream>>>(xs, xb, rowStart, deg, srcU16, dinv, Wt,
                                   bg, lw, lb, out);
}